// Round 11
// baseline (252.174 us; speedup 1.0000x reference)
//
#include <hip/hip_runtime.h>
#include <math.h>

constexpr int H = 64;
constexpr int FIN = 128;
constexpr int BIN_SHIFT = 8;          // 256 nodes per bin
constexpr int BIN_NODES = 1 << BIN_SHIFT;
constexpr int MAX_BINS = 512;         // supports N <= 131072
constexpr int BIN_CAP = 10240;        // mean 8192 + ~22 sigma
constexpr int SRC_BITS = 24;          // word = dstLow8 << 24 | src  (N < 2^24)
constexpr unsigned SRC_MASK = (1u << SRC_BITS) - 1;
constexpr int KB_BLOCKS = 1024;
constexpr int KB_ITER = 13;           // fast path covers E <= 1024*256*13 = 3.4M

typedef __attribute__((ext_vector_type(8))) __bf16 bf16x8;
typedef __attribute__((ext_vector_type(4))) float f32x4;
typedef __attribute__((ext_vector_type(2))) float f32x2;

__device__ inline float bf2f(unsigned short u) {
    unsigned v = ((unsigned)u) << 16;
    return __builtin_bit_cast(float, v);
}
__device__ inline unsigned short f2bf(float f) {
    unsigned u = __builtin_bit_cast(unsigned, f);
    unsigned rnd = 0x7FFFu + ((u >> 16) & 1u);   // RTN-even
    return (unsigned short)((u + rnd) >> 16);
}
__device__ inline float bflo(unsigned u) { return __builtin_bit_cast(float, u << 16); }
__device__ inline float bfhi(unsigned u) { return __builtin_bit_cast(float, u & 0xFFFF0000u); }

__device__ inline int wave_incl_scan(int v, int lane) {
#pragma unroll
    for (int off = 1; off < 64; off <<= 1) {
        int t = __shfl_up(v, off);
        if (lane >= off) v += t;
    }
    return v;
}

// ---------------- cursor init: cursor[b] = b * BIN_CAP ----------------
__global__ void k_initcur(int* __restrict__ cursor, int nbins) {
    int i = blockIdx.x * blockDim.x + threadIdx.x;
    if (i < nbins) cursor[i] = i * BIN_CAP;
}

// ---------------- bin scatter: LDS hist -> LDS-staged ordered scatter -> int4 run flush ----------------
__global__ __launch_bounds__(256) void k_bin(
    const int* __restrict__ src, const int* __restrict__ dst, int E, int nbins,
    int* __restrict__ cursor, int* __restrict__ binned) {
    __shared__ int hist[MAX_BINS];
    __shared__ int base[MAX_BINS];
    __shared__ int loff[MAX_BINS];
    __shared__ int words[KB_ITER * 256];   // 13.3 KB block-local staged payload
    __shared__ int wsum[4];
    int tid = threadIdx.x, lane = tid & 63, wid = tid >> 6;
    long long e0 = (long long)E * blockIdx.x / gridDim.x;
    long long e1 = (long long)E * (blockIdx.x + 1) / gridDim.x;
    int chunk = (int)(e1 - e0);
    for (int i = tid; i < MAX_BINS; i += 256) hist[i] = 0;
    __syncthreads();
    // phase 1: count + keep (bin, dstLow, rank) in registers.  [b:10][dl:8][r:14]
    int packed[KB_ITER];
#pragma unroll
    for (int i = 0; i < KB_ITER; ++i) {
        int o = i * 256 + tid;
        packed[i] = -1;
        if (o < chunk) {
            int d = dst[e0 + o];
            int b = d >> BIN_SHIFT;
            int r = atomicAdd(&hist[b], 1);   // r < chunk <= 3328 < 2^14
            packed[i] = (b << 22) | ((d & (BIN_NODES - 1)) << 14) | r;
        }
    }
    __syncthreads();
    // phase 1.5: block-local exclusive scan of hist (2 bins / thread) + global run reservation
    {
        int b0 = tid * 2;
        int c0 = hist[b0], c1 = hist[b0 + 1];
        int s = c0 + c1;
        int incl = wave_incl_scan(s, lane);
        if (lane == 63) wsum[wid] = incl;
        __syncthreads();
        int woff = 0;
        for (int w = 0; w < wid; ++w) woff += wsum[w];
        int ex = woff + incl - s;
        loff[b0] = ex;
        loff[b0 + 1] = ex + c0;
        if (b0 < nbins && c0) base[b0] = atomicAdd(&cursor[b0], c0);
        if (b0 + 1 < nbins && c1) base[b0 + 1] = atomicAdd(&cursor[b0 + 1], c1);
    }
    __syncthreads();
    // phase 2: scatter payload into LDS, ordered by bin
#pragma unroll
    for (int i = 0; i < KB_ITER; ++i) {
        int o = i * 256 + tid;
        if (o < chunk) {
            unsigned w = (unsigned)packed[i];
            int b = (int)(w >> 22);
            int dl = (int)((w >> 14) & 0xFF);
            int r = (int)(w & 0x3FFF);
            words[loff[b] + r] = (int)(((unsigned)dl << SRC_BITS) | (unsigned)src[e0 + o]);
        }
    }
    __syncthreads();
    // phase 3: flush each run contiguously (aligned int4 bursts -> full-sector writes)
    for (int b = tid; b < nbins; b += 256) {
        int n = hist[b];
        if (!n) continue;
        int g = base[b];
        int l = loff[b];
        int i = 0;
        while (i < n && ((g + i) & 3)) { binned[g + i] = words[l + i]; ++i; }
        for (; i + 4 <= n; i += 4) {
            int4 v = make_int4(words[l + i], words[l + i + 1], words[l + i + 2], words[l + i + 3]);
            *(int4*)&binned[g + i] = v;
        }
        for (; i < n; ++i) binned[g + i] = words[l + i];
    }
    // slow-path tail (only if chunk > KB_ITER*256; empty for E=3.2M)
    for (int o = KB_ITER * 256 + tid; o < chunk; o += 256) {
        int d = dst[e0 + o];
        int b = d >> BIN_SHIFT;
        int r = atomicAdd(&cursor[b], 1);
        binned[r] = (int)(((unsigned)(d & (BIN_NODES - 1)) << SRC_BITS) | (unsigned)src[e0 + o]);
    }
}

// ---------------- bin scan: binbase = exclscan(cursor[b] - b*CAP) ----------------
__global__ __launch_bounds__(256) void k_binscan(
    const int* __restrict__ cursor, int nbins,
    int* __restrict__ binbase, int* __restrict__ rowptr, int N, int E) {
    __shared__ int wsum[4];
    int tid = threadIdx.x, lane = tid & 63, wid = tid >> 6;
    int b0 = tid * 4;
    int c[4];
#pragma unroll
    for (int k = 0; k < 4; ++k) {
        int b = b0 + k;
        c[k] = (b < nbins) ? cursor[b] - b * BIN_CAP : 0;
    }
    int t = c[0] + c[1] + c[2] + c[3];
    int incl = wave_incl_scan(t, lane);
    if (lane == 63) wsum[wid] = incl;
    __syncthreads();
    int woff = 0;
    for (int w = 0; w < wid; ++w) woff += wsum[w];
    int p = woff + incl - t;
#pragma unroll
    for (int k = 0; k < 4; ++k) {
        int b = b0 + k;
        if (b < nbins) binbase[b] = p;
        p += c[k];
    }
    if (tid == 0) rowptr[N] = E;
}

// ---------------- per-bin sort: csr_src + rowptr + dinv, all LDS-local ----------------
__global__ __launch_bounds__(256) void k_binsort(
    const int* __restrict__ cursor, const int* __restrict__ binbase,
    const int* __restrict__ binned, int N,
    int* __restrict__ csr_src, int* __restrict__ rowptr, float* __restrict__ dinv) {
    __shared__ int cnt[BIN_NODES];
    __shared__ int excl[BIN_NODES];
    __shared__ int rnk[BIN_NODES];
    __shared__ int wsum[4];
    int bin = blockIdx.x;
    int tid = threadIdx.x, lane = tid & 63, wid = tid >> 6;
    int n = cursor[bin] - bin * BIN_CAP;
    int gbase = binbase[bin];
    const int* bp = binned + (size_t)bin * BIN_CAP;
    cnt[tid] = 0; rnk[tid] = 0;
    __syncthreads();
    for (int i = tid; i < n; i += 256)
        atomicAdd(&cnt[((unsigned)bp[i]) >> SRC_BITS], 1);
    __syncthreads();
    int v = cnt[tid];
    int incl = wave_incl_scan(v, lane);
    if (lane == 63) wsum[wid] = incl;
    __syncthreads();
    int woff = 0;
    for (int w = 0; w < wid; ++w) woff += wsum[w];
    int ex = woff + incl - v;
    excl[tid] = ex;
    int node = bin * BIN_NODES + tid;
    if (node < N) {
        rowptr[node] = gbase + ex;
        dinv[node] = 1.0f / sqrtf((float)v + 1.0f);  // +1 self-loop
    }
    __syncthreads();
    for (int i = tid; i < n; i += 256) {
        unsigned w = (unsigned)bp[i];
        int dl = w >> SRC_BITS;
        int r = atomicAdd(&rnk[dl], 1);
        csr_src[gbase + excl[dl] + r] = (int)(w & SRC_MASK);
    }
}

// ---------------- MFMA GEMM: A16 = bf16((f(X) @ W) * dinv), f = relu(.+bias) if RELU_IN ----------------
template<int K, bool RELU_IN>
__global__ __launch_bounds__(256) void k_mgemm(
    const float* __restrict__ X, const float* __restrict__ W,
    const float* __restrict__ bias, const float* __restrict__ dinv,
    int N, unsigned short* __restrict__ A16) {
    constexpr int LDK = K + 8;
    __shared__ short sX[64 * LDK];
    __shared__ short sWt[64 * LDK];
    int tid = threadIdx.x;
    // stage W transposed: sWt[c][k] = bf16(W[k][c])   (coalesced global read)
    for (int idx = tid; idx < K * 64; idx += 256) {
        int k = idx >> 6, c = idx & 63;
        sWt[c * LDK + k] = (short)f2bf(W[idx]);
    }
    // stage X rows as bf16 (optional relu(x+bias)), packed 2-at-a-time
    {
        int row = tid >> 2;
        int q0 = (tid & 3) * (K / 4);
        int grow = blockIdx.x * 64 + row;
        const float* xp = X + (size_t)grow * K + q0;
        unsigned* dstp = (unsigned*)&sX[row * LDK + q0];
#pragma unroll
        for (int i = 0; i < K / 16; ++i) {
            float4 v = make_float4(0.f, 0.f, 0.f, 0.f);
            if (grow < N) v = *(const float4*)(xp + i * 4);
            if (RELU_IN) {
                float4 bb = *(const float4*)(bias + q0 + i * 4);
                v.x = fmaxf(v.x + bb.x, 0.f); v.y = fmaxf(v.y + bb.y, 0.f);
                v.z = fmaxf(v.z + bb.z, 0.f); v.w = fmaxf(v.w + bb.w, 0.f);
            }
            unsigned lo = (unsigned)f2bf(v.x) | ((unsigned)f2bf(v.y) << 16);
            unsigned hi = (unsigned)f2bf(v.z) | ((unsigned)f2bf(v.w) << 16);
            dstp[i * 2] = lo;
            dstp[i * 2 + 1] = hi;
        }
    }
    __syncthreads();
    int w = tid >> 6, lane = tid & 63;
    int mrow = lane & 15, kgrp = lane >> 4;
    f32x4 acc[4] = {};
    const short* xbase = &sX[(16 * w + mrow) * LDK + kgrp * 8];
    const short* wbase = &sWt[mrow * LDK + kgrp * 8];
#pragma unroll
    for (int t = 0; t < K / 32; ++t) {
        bf16x8 a = *(const bf16x8*)(xbase + 32 * t);
#pragma unroll
        for (int c = 0; c < 4; ++c) {
            bf16x8 b = *(const bf16x8*)(wbase + 16 * c * LDK + 32 * t);
            acc[c] = __builtin_amdgcn_mfma_f32_16x16x32_bf16(a, b, acc[c], 0, 0, 0);
        }
    }
    // C/D layout (m89-verified): col = lane&15, row_in_tile = (lane>>4)*4 + reg
    int r0g = blockIdx.x * 64 + 16 * w + kgrp * 4;
#pragma unroll
    for (int r = 0; r < 4; ++r) {
        int rg = r0g + r;
        if (rg < N) {
            float dv = dinv[rg];
#pragma unroll
            for (int c = 0; c < 4; ++c)
                A16[(size_t)rg * H + 16 * c + mrow] = f2bf(acc[c][r] * dv);
        }
    }
}

// ---------------- gather: row = dinv[n] * (A[n] + sum_{s in in(n)} A[s]),  A in bf16 ----------------
// 8 groups of 8 lanes; lane owns features [8sub..8sub+7] as one uint4 (16 B) load.
// 4-deep ILP: 32 edges per iter, 4 independent loads + 4 accumulator sets in flight.
__device__ inline void acc8(f32x2* acc, uint4 u) {
    f32x2 v0 = {bflo(u.x), bfhi(u.x)};
    f32x2 v1 = {bflo(u.y), bfhi(u.y)};
    f32x2 v2 = {bflo(u.z), bfhi(u.z)};
    f32x2 v3 = {bflo(u.w), bfhi(u.w)};
    acc[0] += v0; acc[1] += v1; acc[2] += v2; acc[3] += v3;
}

template<bool FUSE>
__global__ __launch_bounds__(256) void k_gather(
    const int* __restrict__ rowptr, const int* __restrict__ csr_src,
    const float* __restrict__ dinv, const unsigned short* __restrict__ A16,
    float* __restrict__ B, int N,
    const float* __restrict__ b2, const float* __restrict__ Wt, const float* __restrict__ bt,
    const float* __restrict__ We, const float* __restrict__ be, float* __restrict__ out) {
    int node = blockIdx.x * 4 + (threadIdx.x >> 6);
    if (node >= N) return;
    int lane = threadIdx.x & 63;
    int grp = lane >> 3, sub = lane & 7;
    const uint4* A8 = (const uint4*)A16;     // row = 8 x uint4
    int beg = rowptr[node], end = rowptr[node + 1];
    f32x2 a0[4] = {}, a1[4] = {}, a2[4] = {}, a3[4] = {};
    if (grp == 0) acc8(a0, A8[(size_t)node * 8 + sub]);   // self-loop term
    for (int e0 = beg; e0 < end; e0 += 64) {
        int m = end - e0; if (m > 64) m = 64;
        int id = (lane < m) ? csr_src[e0 + lane] : 0;
        int c = 0;
        for (; c + 32 <= m; c += 32) {
            int s0 = __shfl(id, c + grp);
            int s1 = __shfl(id, c + 8 + grp);
            int s2 = __shfl(id, c + 16 + grp);
            int s3 = __shfl(id, c + 24 + grp);
            uint4 u0 = A8[(size_t)s0 * 8 + sub];
            uint4 u1 = A8[(size_t)s1 * 8 + sub];
            uint4 u2 = A8[(size_t)s2 * 8 + sub];
            uint4 u3 = A8[(size_t)s3 * 8 + sub];
            acc8(a0, u0); acc8(a1, u1); acc8(a2, u2); acc8(a3, u3);
        }
        for (; c + 16 <= m; c += 16) {
            int s0 = __shfl(id, c + grp);
            int s1 = __shfl(id, c + 8 + grp);
            uint4 u0 = A8[(size_t)s0 * 8 + sub];
            uint4 u1 = A8[(size_t)s1 * 8 + sub];
            acc8(a0, u0); acc8(a1, u1);
        }
        for (; c < m; c += 8) {
            int cc = c + grp;
            int s = __shfl(id, cc < m ? cc : 0);
            if (cc < m) acc8(a0, A8[(size_t)s * 8 + sub]);
        }
    }
#pragma unroll
    for (int j = 0; j < 4; ++j) a0[j] += (a1[j] + (a2[j] + a3[j]));
    // cross-group reduce (same sub, groups differ by lane bits 3..5)
#pragma unroll
    for (int off = 8; off < 64; off <<= 1) {
#pragma unroll
        for (int j = 0; j < 4; ++j) {
            a0[j][0] += __shfl_xor(a0[j][0], off);
            a0[j][1] += __shfl_xor(a0[j][1], off);
        }
    }
    if (grp == 0) {
        float dv = dinv[node];
        float r[8];
#pragma unroll
        for (int j = 0; j < 4; ++j) { r[2 * j] = a0[j][0] * dv; r[2 * j + 1] = a0[j][1] * dv; }
        if (!FUSE) {
            float* bp = B + (size_t)node * H + sub * 8;
            *(float4*)bp = make_float4(r[0], r[1], r[2], r[3]);
            *(float4*)(bp + 4) = make_float4(r[4], r[5], r[6], r[7]);
        } else {
            int f = sub * 8;
            float p1 = 0.f, p2 = 0.f;
#pragma unroll
            for (int j = 0; j < 8; ++j) {
                float g = fmaxf(r[j] + b2[f + j], 0.f);
                p1 += g * Wt[f + j];
                p2 += g * We[f + j];
            }
#pragma unroll
            for (int off = 1; off < 8; off <<= 1) {
                p1 += __shfl_xor(p1, off);
                p2 += __shfl_xor(p2, off);
            }
            if (sub == 0) {
                out[node] = p1 + bt[0];
                out[N + node] = p2 + be[0];
            }
        }
    }
}

extern "C" void kernel_launch(void* const* d_in, const int* in_sizes, int n_in,
                              void* d_out, int out_size, void* d_ws, size_t ws_size,
                              hipStream_t stream) {
    const float* x  = (const float*)d_in[0];
    const int* edge = (const int*)d_in[1];
    const float* W1 = (const float*)d_in[2];
    const float* b1 = (const float*)d_in[3];
    const float* W2 = (const float*)d_in[4];
    const float* b2 = (const float*)d_in[5];
    const float* Wt = (const float*)d_in[6];
    const float* bt = (const float*)d_in[7];
    const float* We = (const float*)d_in[8];
    const float* be = (const float*)d_in[9];

    int N = in_sizes[0] / FIN;
    int E = in_sizes[1] / 2;
    const int* src = edge;
    const int* dst = edge + E;
    int nbins = (N + BIN_NODES - 1) >> BIN_SHIFT;

    char* ws = (char*)d_ws;
    size_t off = 0;
    auto alloc = [&](size_t bytes) {
        void* p = ws + off;
        off += (bytes + 255) & ~size_t(255);
        return p;
    };
    float* dinv    = (float*)alloc((size_t)N * sizeof(float));
    int*   rowptr  = (int*)alloc((size_t)(N + 1) * sizeof(int));
    int*   cursor  = (int*)alloc((size_t)nbins * sizeof(int));
    int*   binbase = (int*)alloc((size_t)nbins * sizeof(int));
    int*   binned  = (int*)alloc((size_t)nbins * BIN_CAP * sizeof(int));
    int*   csr_src = (int*)alloc((size_t)E * sizeof(int));
    unsigned short* A16 = (unsigned short*)alloc((size_t)N * H * sizeof(unsigned short));
    float* B       = (float*)alloc((size_t)N * H * sizeof(float));

    // CSR build via two-level bin sort (no per-edge global atomics)
    k_initcur<<<(nbins + 255) / 256, 256, 0, stream>>>(cursor, nbins);
    k_bin<<<KB_BLOCKS, 256, 0, stream>>>(src, dst, E, nbins, cursor, binned);
    k_binscan<<<1, 256, 0, stream>>>(cursor, nbins, binbase, rowptr, N, E);
    k_binsort<<<nbins, 256, 0, stream>>>(cursor, binbase, binned, N, csr_src, rowptr, dinv);

    int ggrid = (N + 63) / 64;
    // layer 1
    k_mgemm<FIN, false><<<ggrid, 256, 0, stream>>>(x, W1, nullptr, dinv, N, A16);
    k_gather<false><<<(N + 3) / 4, 256, 0, stream>>>(rowptr, csr_src, dinv, A16, B, N,
                                                     nullptr, nullptr, nullptr, nullptr, nullptr, nullptr);

    // layer 2 + fused heads
    k_mgemm<H, true><<<ggrid, 256, 0, stream>>>(B, W2, b1, dinv, N, A16);
    k_gather<true><<<(N + 3) / 4, 256, 0, stream>>>(rowptr, csr_src, dinv, A16, nullptr, N,
                                                    b2, Wt, bt, We, be, (float*)d_out);
}

// Round 12
// 215.656 us; speedup vs baseline: 1.1693x; 1.1693x over previous
//
#include <hip/hip_runtime.h>
#include <math.h>

constexpr int H = 64;
constexpr int FIN = 128;
constexpr int BIN_SHIFT = 8;          // 256 nodes per bin
constexpr int BIN_NODES = 1 << BIN_SHIFT;
constexpr int MAX_BINS = 512;         // supports N <= 131072
constexpr int BIN_CAP = 10240;        // mean 8192 + ~22 sigma
constexpr int SRC_BITS = 24;          // word = dstLow8 << 24 | src  (N < 2^24)
constexpr unsigned SRC_MASK = (1u << SRC_BITS) - 1;
constexpr int KB_TPB = 512;
constexpr int KB_BLOCKS = 512;
constexpr int KB_ITER = 13;           // fast path covers E <= 512*512*13 = 3.4M

typedef __attribute__((ext_vector_type(8))) __bf16 bf16x8;
typedef __attribute__((ext_vector_type(4))) float f32x4;
typedef __attribute__((ext_vector_type(2))) float f32x2;

__device__ inline float bf2f(unsigned short u) {
    unsigned v = ((unsigned)u) << 16;
    return __builtin_bit_cast(float, v);
}
__device__ inline unsigned short f2bf(float f) {
    unsigned u = __builtin_bit_cast(unsigned, f);
    unsigned rnd = 0x7FFFu + ((u >> 16) & 1u);   // RTN-even
    return (unsigned short)((u + rnd) >> 16);
}
__device__ inline float bflo(unsigned u) { return __builtin_bit_cast(float, u << 16); }
__device__ inline float bfhi(unsigned u) { return __builtin_bit_cast(float, u & 0xFFFF0000u); }

__device__ inline int wave_incl_scan(int v, int lane) {
#pragma unroll
    for (int off = 1; off < 64; off <<= 1) {
        int t = __shfl_up(v, off);
        if (lane >= off) v += t;
    }
    return v;
}

// ---------------- cursor init: cursor[b] = b * BIN_CAP ----------------
__global__ void k_initcur(int* __restrict__ cursor, int nbins) {
    int i = blockIdx.x * blockDim.x + threadIdx.x;
    if (i < nbins) cursor[i] = i * BIN_CAP;
}

// ---------------- bin scatter: 512-thread blocks (16 waves/CU), LDS-staged ordered scatter ----------------
__global__ __launch_bounds__(512) void k_bin(
    const int* __restrict__ src, const int* __restrict__ dst, int E, int nbins,
    int* __restrict__ cursor, int* __restrict__ binned) {
    __shared__ int hist[MAX_BINS];
    __shared__ int base[MAX_BINS];
    __shared__ int loff[MAX_BINS];
    __shared__ int words[KB_ITER * KB_TPB];   // 26.6 KB block-local staged payload
    __shared__ int wsum[8];
    int tid = threadIdx.x, lane = tid & 63, wid = tid >> 6;
    long long e0 = (long long)E * blockIdx.x / gridDim.x;
    long long e1 = (long long)E * (blockIdx.x + 1) / gridDim.x;
    int chunk = (int)(e1 - e0);
    for (int i = tid; i < MAX_BINS; i += KB_TPB) hist[i] = 0;
    __syncthreads();
    // phase 1: count + keep (bin, dstLow, rank) in registers.  [b:10][dl:8][r:14]
    int packed[KB_ITER];
#pragma unroll
    for (int i = 0; i < KB_ITER; ++i) {
        int o = i * KB_TPB + tid;
        packed[i] = -1;
        if (o < chunk) {
            int d = dst[e0 + o];
            int b = d >> BIN_SHIFT;
            int r = atomicAdd(&hist[b], 1);   // r < chunk <= 6656 < 2^14
            packed[i] = (b << 22) | ((d & (BIN_NODES - 1)) << 14) | r;
        }
    }
    __syncthreads();
    // phase 1.5: block-local exclusive scan of hist (1 bin / thread) + global run reservation
    {
        int c0 = hist[tid];
        int incl = wave_incl_scan(c0, lane);
        if (lane == 63) wsum[wid] = incl;
        __syncthreads();
        int woff = 0;
        for (int w = 0; w < wid; ++w) woff += wsum[w];
        int ex = woff + incl - c0;
        loff[tid] = ex;
        if (tid < nbins && c0) base[tid] = atomicAdd(&cursor[tid], c0);
    }
    __syncthreads();
    // phase 2: scatter payload into LDS, ordered by bin
#pragma unroll
    for (int i = 0; i < KB_ITER; ++i) {
        int o = i * KB_TPB + tid;
        if (o < chunk) {
            unsigned w = (unsigned)packed[i];
            int b = (int)(w >> 22);
            int dl = (int)((w >> 14) & 0xFF);
            int r = (int)(w & 0x3FFF);
            words[loff[b] + r] = (int)(((unsigned)dl << SRC_BITS) | (unsigned)src[e0 + o]);
        }
    }
    __syncthreads();
    // phase 3: flush each run contiguously (aligned int4 bursts -> full-sector writes)
    for (int b = tid; b < nbins; b += KB_TPB) {
        int n = hist[b];
        if (!n) continue;
        int g = base[b];
        int l = loff[b];
        int i = 0;
        while (i < n && ((g + i) & 3)) { binned[g + i] = words[l + i]; ++i; }
        for (; i + 4 <= n; i += 4) {
            int4 v = make_int4(words[l + i], words[l + i + 1], words[l + i + 2], words[l + i + 3]);
            *(int4*)&binned[g + i] = v;
        }
        for (; i < n; ++i) binned[g + i] = words[l + i];
    }
    // slow-path tail (only if chunk > KB_ITER*KB_TPB; empty for E=3.2M)
    for (int o = KB_ITER * KB_TPB + tid; o < chunk; o += KB_TPB) {
        int d = dst[e0 + o];
        int b = d >> BIN_SHIFT;
        int r = atomicAdd(&cursor[b], 1);
        binned[r] = (int)(((unsigned)(d & (BIN_NODES - 1)) << SRC_BITS) | (unsigned)src[e0 + o]);
    }
}

// ---------------- bin scan: binbase = exclscan(cursor[b] - b*CAP) ----------------
__global__ __launch_bounds__(256) void k_binscan(
    const int* __restrict__ cursor, int nbins,
    int* __restrict__ binbase, int* __restrict__ rowptr, int N, int E) {
    __shared__ int wsum[4];
    int tid = threadIdx.x, lane = tid & 63, wid = tid >> 6;
    int b0 = tid * 4;
    int c[4];
#pragma unroll
    for (int k = 0; k < 4; ++k) {
        int b = b0 + k;
        c[k] = (b < nbins) ? cursor[b] - b * BIN_CAP : 0;
    }
    int t = c[0] + c[1] + c[2] + c[3];
    int incl = wave_incl_scan(t, lane);
    if (lane == 63) wsum[wid] = incl;
    __syncthreads();
    int woff = 0;
    for (int w = 0; w < wid; ++w) woff += wsum[w];
    int p = woff + incl - t;
#pragma unroll
    for (int k = 0; k < 4; ++k) {
        int b = b0 + k;
        if (b < nbins) binbase[b] = p;
        p += c[k];
    }
    if (tid == 0) rowptr[N] = E;
}

// ---------------- per-bin sort: 512-thread blocks; csr_src + rowptr + dinv ----------------
__global__ __launch_bounds__(512) void k_binsort(
    const int* __restrict__ cursor, const int* __restrict__ binbase,
    const int* __restrict__ binned, int N,
    int* __restrict__ csr_src, int* __restrict__ rowptr, float* __restrict__ dinv) {
    __shared__ int cnt[BIN_NODES];
    __shared__ int excl[BIN_NODES];
    __shared__ int rnk[BIN_NODES];
    __shared__ int wsum[4];
    int bin = blockIdx.x;
    int tid = threadIdx.x, lane = tid & 63, wid = tid >> 6;
    int n = cursor[bin] - bin * BIN_CAP;
    int gbase = binbase[bin];
    const int* bp = binned + (size_t)bin * BIN_CAP;
    if (tid < BIN_NODES) { cnt[tid] = 0; rnk[tid] = 0; }
    __syncthreads();
    for (int i = tid; i < n; i += 512)
        atomicAdd(&cnt[((unsigned)bp[i]) >> SRC_BITS], 1);
    __syncthreads();
    int v = 0, incl = 0;
    if (tid < BIN_NODES) {
        v = cnt[tid];
        incl = wave_incl_scan(v, lane);
        if (lane == 63) wsum[wid] = incl;
    }
    __syncthreads();
    if (tid < BIN_NODES) {
        int woff = 0;
        for (int w = 0; w < wid; ++w) woff += wsum[w];
        int ex = woff + incl - v;
        excl[tid] = ex;
        int node = bin * BIN_NODES + tid;
        if (node < N) {
            rowptr[node] = gbase + ex;
            dinv[node] = 1.0f / sqrtf((float)v + 1.0f);  // +1 self-loop
        }
    }
    __syncthreads();
    for (int i = tid; i < n; i += 512) {
        unsigned w = (unsigned)bp[i];
        int dl = w >> SRC_BITS;
        int r = atomicAdd(&rnk[dl], 1);
        csr_src[gbase + excl[dl] + r] = (int)(w & SRC_MASK);
    }
}

// ---------------- MFMA GEMM: A16 = bf16((f(X) @ W) * dinv), f = relu(.+bias) if RELU_IN ----------------
template<int K, bool RELU_IN>
__global__ __launch_bounds__(256) void k_mgemm(
    const float* __restrict__ X, const float* __restrict__ W,
    const float* __restrict__ bias, const float* __restrict__ dinv,
    int N, unsigned short* __restrict__ A16) {
    constexpr int LDK = K + 8;
    __shared__ short sX[64 * LDK];
    __shared__ short sWt[64 * LDK];
    int tid = threadIdx.x;
    // stage W transposed: sWt[c][k] = bf16(W[k][c])   (coalesced global read)
    for (int idx = tid; idx < K * 64; idx += 256) {
        int k = idx >> 6, c = idx & 63;
        sWt[c * LDK + k] = (short)f2bf(W[idx]);
    }
    // stage X rows as bf16 (optional relu(x+bias)), packed 2-at-a-time
    {
        int row = tid >> 2;
        int q0 = (tid & 3) * (K / 4);
        int grow = blockIdx.x * 64 + row;
        const float* xp = X + (size_t)grow * K + q0;
        unsigned* dstp = (unsigned*)&sX[row * LDK + q0];
#pragma unroll
        for (int i = 0; i < K / 16; ++i) {
            float4 v = make_float4(0.f, 0.f, 0.f, 0.f);
            if (grow < N) v = *(const float4*)(xp + i * 4);
            if (RELU_IN) {
                float4 bb = *(const float4*)(bias + q0 + i * 4);
                v.x = fmaxf(v.x + bb.x, 0.f); v.y = fmaxf(v.y + bb.y, 0.f);
                v.z = fmaxf(v.z + bb.z, 0.f); v.w = fmaxf(v.w + bb.w, 0.f);
            }
            unsigned lo = (unsigned)f2bf(v.x) | ((unsigned)f2bf(v.y) << 16);
            unsigned hi = (unsigned)f2bf(v.z) | ((unsigned)f2bf(v.w) << 16);
            dstp[i * 2] = lo;
            dstp[i * 2 + 1] = hi;
        }
    }
    __syncthreads();
    int w = tid >> 6, lane = tid & 63;
    int mrow = lane & 15, kgrp = lane >> 4;
    f32x4 acc[4] = {};
    const short* xbase = &sX[(16 * w + mrow) * LDK + kgrp * 8];
    const short* wbase = &sWt[mrow * LDK + kgrp * 8];
#pragma unroll
    for (int t = 0; t < K / 32; ++t) {
        bf16x8 a = *(const bf16x8*)(xbase + 32 * t);
#pragma unroll
        for (int c = 0; c < 4; ++c) {
            bf16x8 b = *(const bf16x8*)(wbase + 16 * c * LDK + 32 * t);
            acc[c] = __builtin_amdgcn_mfma_f32_16x16x32_bf16(a, b, acc[c], 0, 0, 0);
        }
    }
    // C/D layout (m89-verified): col = lane&15, row_in_tile = (lane>>4)*4 + reg
    int r0g = blockIdx.x * 64 + 16 * w + kgrp * 4;
#pragma unroll
    for (int r = 0; r < 4; ++r) {
        int rg = r0g + r;
        if (rg < N) {
            float dv = dinv[rg];
#pragma unroll
            for (int c = 0; c < 4; ++c)
                A16[(size_t)rg * H + 16 * c + mrow] = f2bf(acc[c][r] * dv);
        }
    }
}

// ---------------- gather: row = dinv[n] * (A[n] + sum_{s in in(n)} A[s]),  A in bf16 ----------------
// 2 nodes per wave (id loads + self rows for both issued up front -> latency hiding);
// 8 groups of 8 lanes; lane owns features [8sub..8sub+7] as one uint4 (16 B) load; 2-deep ILP.
__device__ inline void acc8(f32x2* acc, uint4 u) {
    f32x2 v0 = {bflo(u.x), bfhi(u.x)};
    f32x2 v1 = {bflo(u.y), bfhi(u.y)};
    f32x2 v2 = {bflo(u.z), bfhi(u.z)};
    f32x2 v3 = {bflo(u.w), bfhi(u.w)};
    acc[0] += v0; acc[1] += v1; acc[2] += v2; acc[3] += v3;
}

template<bool FUSE>
__global__ __launch_bounds__(256) void k_gather(
    const int* __restrict__ rowptr, const int* __restrict__ csr_src,
    const float* __restrict__ dinv, const unsigned short* __restrict__ A16,
    float* __restrict__ B, int N,
    const float* __restrict__ b2, const float* __restrict__ Wt, const float* __restrict__ bt,
    const float* __restrict__ We, const float* __restrict__ be, float* __restrict__ out) {
    int w = threadIdx.x >> 6;
    int lane = threadIdx.x & 63;
    int grp = lane >> 3, sub = lane & 7;
    const uint4* A8 = (const uint4*)A16;     // row = 8 x uint4
    int nodeA = blockIdx.x * 8 + w;
    int nodeB = nodeA + 4;
    int begA = 0, endA = 0, begB = 0, endB = 0;
    if (nodeA < N) { begA = rowptr[nodeA]; endA = rowptr[nodeA + 1]; }
    if (nodeB < N) { begB = rowptr[nodeB]; endB = rowptr[nodeB + 1]; }
    // issue both first-chunk id loads up front
    int mA0 = endA - begA; if (mA0 > 64) mA0 = 64;
    int mB0 = endB - begB; if (mB0 > 64) mB0 = 64;
    int idA = (lane < mA0) ? csr_src[begA + lane] : 0;
    int idB = (lane < mB0) ? csr_src[begB + lane] : 0;
    f32x2 aA[4] = {}, aB[4] = {};
    if (grp == 0 && nodeA < N) acc8(aA, A8[(size_t)nodeA * 8 + sub]);   // self-loop terms
    if (grp == 0 && nodeB < N) acc8(aB, A8[(size_t)nodeB * 8 + sub]);

    auto gather_node = [&](int beg, int end, int idFirst, f32x2* acc) {
        f32x2 t[4] = {};
        for (int e0 = beg; e0 < end; e0 += 64) {
            int m = end - e0; if (m > 64) m = 64;
            int id = (e0 == beg) ? idFirst : ((lane < m) ? csr_src[e0 + lane] : 0);
            int c = 0;
            for (; c + 16 <= m; c += 16) {
                int s0 = __shfl(id, c + grp);
                int s1 = __shfl(id, c + 8 + grp);
                uint4 u0 = A8[(size_t)s0 * 8 + sub];
                uint4 u1 = A8[(size_t)s1 * 8 + sub];
                acc8(acc, u0);
                acc8(t, u1);
            }
            for (; c < m; c += 8) {
                int cc = c + grp;
                int s = __shfl(id, cc < m ? cc : 0);
                if (cc < m) acc8(acc, A8[(size_t)s * 8 + sub]);
            }
        }
#pragma unroll
        for (int j = 0; j < 4; ++j) acc[j] += t[j];
    };
    gather_node(begA, endA, idA, aA);
    gather_node(begB, endB, idB, aB);

    // cross-group reduce (same sub, groups differ by lane bits 3..5)
#pragma unroll
    for (int off = 8; off < 64; off <<= 1) {
#pragma unroll
        for (int j = 0; j < 4; ++j) {
            aA[j][0] += __shfl_xor(aA[j][0], off);
            aA[j][1] += __shfl_xor(aA[j][1], off);
            aB[j][0] += __shfl_xor(aB[j][0], off);
            aB[j][1] += __shfl_xor(aB[j][1], off);
        }
    }
    if (grp == 0) {
#pragma unroll
        for (int which = 0; which < 2; ++which) {
            int node = which ? nodeB : nodeA;
            if (node >= N) continue;
            f32x2* a = which ? aB : aA;
            float dv = dinv[node];
            float r[8];
#pragma unroll
            for (int j = 0; j < 4; ++j) { r[2 * j] = a[j][0] * dv; r[2 * j + 1] = a[j][1] * dv; }
            if (!FUSE) {
                float* bp = B + (size_t)node * H + sub * 8;
                *(float4*)bp = make_float4(r[0], r[1], r[2], r[3]);
                *(float4*)(bp + 4) = make_float4(r[4], r[5], r[6], r[7]);
            } else {
                int f = sub * 8;
                float p1 = 0.f, p2 = 0.f;
#pragma unroll
                for (int j = 0; j < 8; ++j) {
                    float g = fmaxf(r[j] + b2[f + j], 0.f);
                    p1 += g * Wt[f + j];
                    p2 += g * We[f + j];
                }
#pragma unroll
                for (int off = 1; off < 8; off <<= 1) {
                    p1 += __shfl_xor(p1, off);
                    p2 += __shfl_xor(p2, off);
                }
                if (sub == 0) {
                    out[node] = p1 + bt[0];
                    out[N + node] = p2 + be[0];
                }
            }
        }
    }
}

extern "C" void kernel_launch(void* const* d_in, const int* in_sizes, int n_in,
                              void* d_out, int out_size, void* d_ws, size_t ws_size,
                              hipStream_t stream) {
    const float* x  = (const float*)d_in[0];
    const int* edge = (const int*)d_in[1];
    const float* W1 = (const float*)d_in[2];
    const float* b1 = (const float*)d_in[3];
    const float* W2 = (const float*)d_in[4];
    const float* b2 = (const float*)d_in[5];
    const float* Wt = (const float*)d_in[6];
    const float* bt = (const float*)d_in[7];
    const float* We = (const float*)d_in[8];
    const float* be = (const float*)d_in[9];

    int N = in_sizes[0] / FIN;
    int E = in_sizes[1] / 2;
    const int* src = edge;
    const int* dst = edge + E;
    int nbins = (N + BIN_NODES - 1) >> BIN_SHIFT;

    char* ws = (char*)d_ws;
    size_t off = 0;
    auto alloc = [&](size_t bytes) {
        void* p = ws + off;
        off += (bytes + 255) & ~size_t(255);
        return p;
    };
    float* dinv    = (float*)alloc((size_t)N * sizeof(float));
    int*   rowptr  = (int*)alloc((size_t)(N + 1) * sizeof(int));
    int*   cursor  = (int*)alloc((size_t)nbins * sizeof(int));
    int*   binbase = (int*)alloc((size_t)nbins * sizeof(int));
    int*   binned  = (int*)alloc((size_t)nbins * BIN_CAP * sizeof(int));
    int*   csr_src = (int*)alloc((size_t)E * sizeof(int));
    unsigned short* A16 = (unsigned short*)alloc((size_t)N * H * sizeof(unsigned short));
    float* B       = (float*)alloc((size_t)N * H * sizeof(float));

    // CSR build via two-level bin sort (no per-edge global atomics)
    k_initcur<<<(nbins + 255) / 256, 256, 0, stream>>>(cursor, nbins);
    k_bin<<<KB_BLOCKS, KB_TPB, 0, stream>>>(src, dst, E, nbins, cursor, binned);
    k_binscan<<<1, 256, 0, stream>>>(cursor, nbins, binbase, rowptr, N, E);
    k_binsort<<<nbins, 512, 0, stream>>>(cursor, binbase, binned, N, csr_src, rowptr, dinv);

    int ggrid = (N + 63) / 64;
    // layer 1
    k_mgemm<FIN, false><<<ggrid, 256, 0, stream>>>(x, W1, nullptr, dinv, N, A16);
    k_gather<false><<<(N + 7) / 8, 256, 0, stream>>>(rowptr, csr_src, dinv, A16, B, N,
                                                     nullptr, nullptr, nullptr, nullptr, nullptr, nullptr);

    // layer 2 + fused heads
    k_mgemm<H, true><<<ggrid, 256, 0, stream>>>(B, W2, b1, dinv, N, A16);
    k_gather<true><<<(N + 7) / 8, 256, 0, stream>>>(rowptr, csr_src, dinv, A16, nullptr, N,
                                                    b2, Wt, bt, We, be, (float*)d_out);
}